// Round 13
// baseline (1080.907 us; speedup 1.0000x reference)
//
#include <hip/hip_runtime.h>

#define BATCH 8
#define T 4096
#define NCH 256
#define NCTX 80
#define NLAYERS 8

typedef unsigned short u16;
typedef __attribute__((ext_vector_type(8))) short short8;
typedef __attribute__((ext_vector_type(4))) short short4v;
typedef __attribute__((ext_vector_type(4))) float float4v;

__device__ __forceinline__ float b2f(u16 u) {
    unsigned v = ((unsigned)u) << 16;
    float f;
    __builtin_memcpy(&f, &v, 4);
    return f;
}
__device__ __forceinline__ u16 f2b(float f) {
    unsigned v;
    __builtin_memcpy(&v, &f, 4);
    unsigned r = v + 0x7FFFu + ((v >> 16) & 1u);
    return (u16)(r >> 16);
}

typedef const __attribute__((address_space(1))) unsigned int* gp1;
typedef __attribute__((address_space(3))) unsigned int* lp3;
__device__ __forceinline__ void gl_lds16(const u16* g, u16* l) {
    __builtin_amdgcn_global_load_lds((gp1)g, (lp3)l, 16, 0, 0);
}

template <bool F32>
__device__ __forceinline__ float LD(const void* p, size_t i) {
    if constexpr (F32) return ((const float*)p)[i];
    else return b2f(((const u16*)p)[i]);
}
template <bool F32>
__device__ __forceinline__ bool skipv(const int* flag) {
    int f = *flag;
    return F32 ? (f != 0) : (f == 0);
}

// ---------------- dtype probe ----------------
__global__ void probe_kernel(const u16* __restrict__ fc, int* __restrict__ flag) {
    __shared__ int cnt;
    if (threadIdx.x == 0) cnt = 0;
    __syncthreads();
    int local = 0;
#pragma unroll
    for (int j = 0; j < 16; j++) {
        u16 u = fc[2 * (threadIdx.x * 16 + j)];
        int e = (u >> 7) & 0xFF;
        if (e >= 0x50 && e <= 0x85) local++;
    }
    atomicAdd(&cnt, local);
    __syncthreads();
    if (threadIdx.x == 0) *flag = (cnt >= 2048) ? 1 : 0;  // 1 = bf16 inputs
}

// ---------------- generic convert to bf16 ----------------
template <bool F32>
__global__ void cvt_kernel(const void* __restrict__ src, u16* __restrict__ dst, int n,
                           const int* __restrict__ flag) {
    if (skipv<F32>(flag)) return;
    int i = blockIdx.x * 256 + threadIdx.x;
    if (i < n) dst[i] = f2b(LD<F32>(src, i));
}

// ---------------- build Wc [8][512][864] ----------------
template <bool F32>
__global__ void prep_wc(const void* __restrict__ in_w, const void* __restrict__ in_b,
                        const void* __restrict__ cond_w, const void* __restrict__ cond_b,
                        u16* __restrict__ Wc, const int* __restrict__ flag) {
    if (skipv<F32>(flag)) return;
    int row = blockIdx.x;  // 0..4095 = l*512+o
    for (int it = 0; it < 4; it++) {
        int col = it * 256 + threadIdx.x;
        if (col >= 864) break;
        float v;
        if (col < 256)       v = LD<F32>(in_w, ((size_t)row * 256 + col) * 3);
        else if (col < 512)  v = LD<F32>(in_w, ((size_t)row * 256 + (col - 256)) * 3 + 1);
        else if (col < 768)  v = LD<F32>(in_w, ((size_t)row * 256 + (col - 512)) * 3 + 2);
        else if (col < 848)  v = LD<F32>(cond_w, (size_t)row * 80 + (col - 768));
        else if (col == 848) v = LD<F32>(in_b, row) + LD<F32>(cond_b, row);
        else                 v = 0.f;
        Wc[(size_t)row * 864 + col] = f2b(v);
    }
}

// ---------------- transpose context -> ctx_t [B][T][96] ----------------
template <bool F32>
__global__ void prep_ctx(const void* __restrict__ ctx, u16* __restrict__ ctxt,
                         const int* __restrict__ flag) {
    if (skipv<F32>(flag)) return;
    __shared__ float sm[80][65];
    const int tid = threadIdx.x;
    const int b = blockIdx.y, t0 = blockIdx.x * 64;
    for (int it = 0; it < 20; it++) {
        int e = it * 256 + tid;
        int j = e >> 6, tt = e & 63;
        sm[j][tt] = LD<F32>(ctx, ((size_t)b * 80 + j) * T + t0 + tt);
    }
    __syncthreads();
    for (int it = 0; it < 24; it++) {
        int e = it * 256 + tid;
        int r = e / 96, c = e - r * 96;
        float v = (c < 80) ? sm[c][r] : (c == 80 ? 1.f : 0.f);
        ctxt[((size_t)b * T + t0 + r) * 96 + c] = f2b(v);
    }
}

// ---------------- start conv (4 -> 256, 1x1) -> x_t [B][T][256] ----------------
template <bool F32>
__global__ void start_kernel(const void* __restrict__ fc, const void* __restrict__ w,
                             const void* __restrict__ bias, u16* __restrict__ xt,
                             const int* __restrict__ flag) {
    if (skipv<F32>(flag)) return;
    __shared__ float fsm[4][64];
    __shared__ float wsm[1024];
    __shared__ float bsm[256];
    const int tid = threadIdx.x;
    const int b = blockIdx.y, t0 = blockIdx.x * 64;
    fsm[tid >> 6][tid & 63] = LD<F32>(fc, ((size_t)b * 8 + (tid >> 6)) * T + t0 + (tid & 63));
    for (int it = 0; it < 4; it++) wsm[it * 256 + tid] = LD<F32>(w, it * 256 + tid);
    bsm[tid] = LD<F32>(bias, tid);
    __syncthreads();
    for (int r = 0; r < 64; r++) {
        int c = tid;
        float a = bsm[c];
#pragma unroll
        for (int k = 0; k < 4; k++) a += wsm[c * 4 + k] * fsm[k][r];
        xt[((size_t)b * T + t0 + r) * 256 + c] = f2b(a);
    }
}

// ================= layer conv kernel: dilated conv+cond GEMM + gate -> acts =================
// grid (T/128=32, B=8, 2) = 512 blocks = 2/CU (breaks the 1-block barrier convoy:
// round 12 counters showed pipe costs SUMMING, not overlapping, at 1 block/CU).
// blockIdx.z splits out-channels: this block handles cols [128z,128z+128) of EACH
// gate half (keeps tanh/sigm pairs together). 512 threads, M=128, N=256, K=864.
// Chunks: 27 K-steps x 2 halves = 54. A triple-buf 3x8KB, B dbuf 2x8KB = 40 KB LDS.
__global__ __launch_bounds__(512, 4) void layer_conv(
    const u16* __restrict__ x, const u16* __restrict__ Wc, const u16* __restrict__ ctxt,
    u16* __restrict__ acts, int layer, int dil) {
    __shared__ u16 lds[20480];  // A: 3x4096 @0 | B: 2x4096 @12288
    const int tid = threadIdx.x;
    const int w = tid >> 6, lane = tid & 63;
    const int l15 = lane & 15, quad = lane >> 4;
    const int iw = w >> 1, jc = w & 1;        // wave: t-rows 32*iw, cols 64*jc (per half)
    const int b = blockIdx.y, t0 = blockIdx.x * 128;
    const int z = blockIdx.z;
    const int co = 128 * z + 64 * jc;         // wave col base within each gate half
    const int lrow = lane >> 2;               // 0..15
    const int lsw = ((lane & 3) ^ (lrow & 3)) * 8;
    const int rq = (quad ^ (l15 & 3)) * 8;

    const u16* xb = x + (size_t)b * T * 256;
    const u16* cb = ctxt + (size_t)b * T * 96;
    const u16* Wl = Wc + (size_t)layer * 512 * 864;

    float4v acc0[2][4], acc1[2][4];  // [m][jj]: acc0 = tanh half, acc1 = sigm half
#pragma unroll
    for (int m = 0; m < 2; m++)
#pragma unroll
        for (int jj = 0; jj < 4; jj++) {
            acc0[m][jj] = (float4v){0.f, 0.f, 0.f, 0.f};
            acc1[m][jj] = (float4v){0.f, 0.f, 0.f, 0.f};
        }

    auto stageA = [&](int s, int abuf) {  // 128 rows x 32 u16; wave w: rows 16w..16w+16
        u16* dst = &lds[abuf * 4096 + w * 512];
        if (s < 24) {
            int seg = s >> 3, cs = s & 7;
            int tb = t0 + 16 * w + (seg - 1) * dil;
            if (tb >= 0 && tb + 16 <= T) {
                gl_lds16(xb + (size_t)(tb + lrow) * 256 + cs * 32 + lsw, dst);
            } else {  // boundary tile: manual masked path (rare)
                int t = tb + lrow;
                short8 av = (short8){0, 0, 0, 0, 0, 0, 0, 0};
                if (t >= 0 && t < T)
                    av = *(const short8*)(xb + (size_t)t * 256 + cs * 32 + lsw);
                *(short4v*)&dst[lane * 8] = __builtin_shufflevector(av, av, 0, 1, 2, 3);
                *(short4v*)&dst[lane * 8 + 4] = __builtin_shufflevector(av, av, 4, 5, 6, 7);
            }
        } else {
            gl_lds16(cb + (size_t)(t0 + 16 * w + lrow) * 96 + (s - 24) * 32 + lsw, dst);
        }
    };
    auto stageB = [&](int c) {  // 128 out-rows x 32 u16; wave w: rows 16w..16w+16
        int s = c >> 1;
        const u16* src =
            Wl + (size_t)((c & 1) * 256 + 128 * z + 16 * w + lrow) * 864 + s * 32 + lsw;
        gl_lds16(src, &lds[12288 + (c & 1) * 4096 + w * 512]);
    };

    stageA(0, 0);
    stageA(1, 1);
    stageB(0);
    __syncthreads();
#pragma unroll 1
    for (int c = 0; c < 54; c++) {
        int s = c >> 1;
        const u16* bA = &lds[(s % 3) * 4096];
        const u16* bB = &lds[12288 + (c & 1) * 4096];
        short8 af0 = *(const short8*)&bA[(32 * iw + l15) * 32 + rq];
        short8 af1 = *(const short8*)&bA[(32 * iw + 16 + l15) * 32 + rq];
        short8 bf[4];
#pragma unroll
        for (int jj = 0; jj < 4; jj++)
            bf[jj] = *(const short8*)&bB[(64 * jc + 16 * jj + l15) * 32 + rq];
        if ((c & 1) == 0 && s + 2 < 27) stageA(s + 2, (s + 2) % 3);
        if (c + 1 < 54) stageB(c + 1);
        if ((c & 1) == 0) {
#pragma unroll
            for (int jj = 0; jj < 4; jj++) {
                acc0[0][jj] = __builtin_amdgcn_mfma_f32_16x16x32_bf16(af0, bf[jj], acc0[0][jj], 0, 0, 0);
                acc0[1][jj] = __builtin_amdgcn_mfma_f32_16x16x32_bf16(af1, bf[jj], acc0[1][jj], 0, 0, 0);
            }
        } else {
#pragma unroll
            for (int jj = 0; jj < 4; jj++) {
                acc1[0][jj] = __builtin_amdgcn_mfma_f32_16x16x32_bf16(af0, bf[jj], acc1[0][jj], 0, 0, 0);
                acc1[1][jj] = __builtin_amdgcn_mfma_f32_16x16x32_bf16(af1, bf[jj], acc1[1][jj], 0, 0, 0);
            }
        }
        __syncthreads();
    }

    // gate + store acts[b][t][o]
    u16* ab = acts + (size_t)b * T * 256;
#pragma unroll
    for (int m = 0; m < 2; m++)
#pragma unroll
        for (int jj = 0; jj < 4; jj++) {
            int o = co + 16 * jj + l15;
#pragma unroll
            for (int r = 0; r < 4; r++) {
                int t = t0 + 32 * iw + 16 * m + quad * 4 + r;
                float at = acc0[m][jj][r], as = acc1[m][jj][r];
                float e2 = __expf(2.f * at);
                float th = 1.f - 2.f / (e2 + 1.f);
                float sg = 1.f / (1.f + __expf(-as));
                ab[(size_t)t * 256 + o] = f2b(th * sg);
            }
        }
}

// ================= layer rs kernel: 1x1 conv (K=256) + residual/skip update =================
// Same z-split skeleton; 8 K-steps x 2 halves = 16 chunks. x updated in place (own tile).
__global__ __launch_bounds__(512, 4) void layer_rs(
    const u16* __restrict__ acts, u16* __restrict__ x, const u16* __restrict__ Wrs,
    const u16* __restrict__ rsb, u16* __restrict__ oacc, int layer, int first, int last) {
    __shared__ u16 lds[20480];
    const int tid = threadIdx.x;
    const int w = tid >> 6, lane = tid & 63;
    const int l15 = lane & 15, quad = lane >> 4;
    const int iw = w >> 1, jc = w & 1;
    const int b = blockIdx.y, t0 = blockIdx.x * 128;
    const int z = blockIdx.z;
    const int co = 128 * z + 64 * jc;
    const int lrow = lane >> 2;
    const int lsw = ((lane & 3) ^ (lrow & 3)) * 8;
    const int rq = (quad ^ (l15 & 3)) * 8;

    const u16* ab = acts + (size_t)b * T * 256;
    const u16* Wr = Wrs + (size_t)layer * 512 * 256;

    float4v acc0[2][4], acc1[2][4];
#pragma unroll
    for (int m = 0; m < 2; m++)
#pragma unroll
        for (int jj = 0; jj < 4; jj++) {
            acc0[m][jj] = (float4v){0.f, 0.f, 0.f, 0.f};
            acc1[m][jj] = (float4v){0.f, 0.f, 0.f, 0.f};
        }

    auto stageA = [&](int s, int abuf) {
        gl_lds16(ab + (size_t)(t0 + 16 * w + lrow) * 256 + s * 32 + lsw,
                 &lds[abuf * 4096 + w * 512]);
    };
    auto stageB = [&](int c) {
        int s = c >> 1;
        const u16* src =
            Wr + (size_t)((c & 1) * 256 + 128 * z + 16 * w + lrow) * 256 + s * 32 + lsw;
        gl_lds16(src, &lds[12288 + (c & 1) * 4096 + w * 512]);
    };

    stageA(0, 0);
    stageA(1, 1);
    stageB(0);
    __syncthreads();
#pragma unroll 1
    for (int c = 0; c < 16; c++) {
        int s = c >> 1;
        const u16* bA = &lds[(s % 3) * 4096];
        const u16* bB = &lds[12288 + (c & 1) * 4096];
        short8 af0 = *(const short8*)&bA[(32 * iw + l15) * 32 + rq];
        short8 af1 = *(const short8*)&bA[(32 * iw + 16 + l15) * 32 + rq];
        short8 bf[4];
#pragma unroll
        for (int jj = 0; jj < 4; jj++)
            bf[jj] = *(const short8*)&bB[(64 * jc + 16 * jj + l15) * 32 + rq];
        if ((c & 1) == 0 && s + 2 < 8) stageA(s + 2, (s + 2) % 3);
        if (c + 1 < 16) stageB(c + 1);
        if ((c & 1) == 0) {
#pragma unroll
            for (int jj = 0; jj < 4; jj++) {
                acc0[0][jj] = __builtin_amdgcn_mfma_f32_16x16x32_bf16(af0, bf[jj], acc0[0][jj], 0, 0, 0);
                acc0[1][jj] = __builtin_amdgcn_mfma_f32_16x16x32_bf16(af1, bf[jj], acc0[1][jj], 0, 0, 0);
            }
        } else {
#pragma unroll
            for (int jj = 0; jj < 4; jj++) {
                acc1[0][jj] = __builtin_amdgcn_mfma_f32_16x16x32_bf16(af0, bf[jj], acc1[0][jj], 0, 0, 0);
                acc1[1][jj] = __builtin_amdgcn_mfma_f32_16x16x32_bf16(af1, bf[jj], acc1[1][jj], 0, 0, 0);
            }
        }
        __syncthreads();
    }

    u16* xv = x + (size_t)b * T * 256;
    u16* oo = oacc + (size_t)b * T * 256;
#pragma unroll
    for (int m = 0; m < 2; m++)
#pragma unroll
        for (int jj = 0; jj < 4; jj++) {
            int o = co + 16 * jj + l15;
            float b0 = b2f(rsb[layer * 512 + o]);
            float b1 = b2f(rsb[layer * 512 + 256 + o]);
#pragma unroll
            for (int r = 0; r < 4; r++) {
                int t = t0 + 32 * iw + 16 * m + quad * 4 + r;
                size_t idx = (size_t)t * 256 + o;
                float v0 = acc0[m][jj][r] + b0;
                if (last) {
                    oo[idx] = f2b(b2f(oo[idx]) + v0);  // last: rs[:256] -> skip
                } else {
                    xv[idx] = f2b(b2f(xv[idx]) + v0);  // residual (in place, own tile)
                    float v1 = acc1[m][jj][r] + b1;
                    oo[idx] = first ? f2b(v1) : f2b(b2f(oo[idx]) + v1);
                }
            }
        }
}

// ---------------- end conv (256 -> 8) + affine + output assembly ----------------
template <bool F32>
__global__ void end_kernel(const u16* __restrict__ oacc, const void* __restrict__ w_end,
                           const void* __restrict__ b_end, const void* __restrict__ fc,
                           void* __restrict__ out, const int* __restrict__ flag) {
    if (skipv<F32>(flag)) return;
    __shared__ float wsm[2048];
    __shared__ float bsm[8];
    const int tid = threadIdx.x;
    for (int it = 0; it < 8; it++) wsm[it * 256 + tid] = LD<F32>(w_end, it * 256 + tid);
    if (tid < 8) bsm[tid] = LD<F32>(b_end, tid);
    __syncthreads();
    int gid = blockIdx.x * 256 + tid;  // 0..32767
    int b = gid >> 12, t = gid & 4095;
    float o8[8];
#pragma unroll
    for (int o = 0; o < 8; o++) o8[o] = bsm[o];
    const u16* orow = oacc + (size_t)(b * T + t) * 256;
    for (int c8 = 0; c8 < 32; c8++) {
        short8 v8 = *(const short8*)(orow + c8 * 8);
#pragma unroll
        for (int k = 0; k < 8; k++) {
            float v = b2f((u16)v8[k]);
            int c = c8 * 8 + k;
#pragma unroll
            for (int o = 0; o < 8; o++) o8[o] += wsm[o * 256 + c] * v;
        }
    }
    size_t ob8 = (size_t)b * 8 * T;
#pragma unroll
    for (int j = 0; j < 4; j++) {
        float f1v = LD<F32>(fc, ob8 + (size_t)(4 + j) * T + t);
        float ls = o8[4 + j];
        float val = __expf(ls) * f1v + o8[j];
        if constexpr (F32) {
            float* o = (float*)out;
            o[ob8 + (size_t)j * T + t] = ((const float*)fc)[ob8 + (size_t)j * T + t];
            o[ob8 + (size_t)(4 + j) * T + t] = val;
            o[(size_t)BATCH * 8 * T + ((size_t)b * 4 + j) * T + t] = ls;
        } else {
            u16* o = (u16*)out;
            o[ob8 + (size_t)j * T + t] = ((const u16*)fc)[ob8 + (size_t)j * T + t];
            o[ob8 + (size_t)(4 + j) * T + t] = f2b(val);
            o[(size_t)BATCH * 8 * T + ((size_t)b * 4 + j) * T + t] = f2b(ls);
        }
    }
}

template <bool F32>
static void launch_prep(const void* forecast, const void* context, const void* start_w,
                        const void* start_b, const void* cond_w, const void* cond_b,
                        const void* in_w, const void* in_b, const void* rs_w, const void* rs_b,
                        u16* xA, u16* ctxt, u16* Wc, u16* Wrs, u16* rsb, const int* flag,
                        hipStream_t stream) {
    cvt_kernel<F32><<<4096, 256, 0, stream>>>(rs_w, Wrs, 8 * 512 * 256, flag);
    cvt_kernel<F32><<<16, 256, 0, stream>>>(rs_b, rsb, 4096, flag);
    prep_wc<F32><<<4096, 256, 0, stream>>>(in_w, in_b, cond_w, cond_b, Wc, flag);
    prep_ctx<F32><<<dim3(64, BATCH), 256, 0, stream>>>(context, ctxt, flag);
    start_kernel<F32><<<dim3(64, BATCH), 256, 0, stream>>>(forecast, start_w, start_b, xA, flag);
}

extern "C" void kernel_launch(void* const* d_in, const int* in_sizes, int n_in,
                              void* d_out, int out_size, void* d_ws, size_t ws_size,
                              hipStream_t stream) {
    const void* forecast = d_in[0];
    const void* context  = d_in[1];
    const void* start_w  = d_in[2];
    const void* start_b  = d_in[3];
    const void* cond_w   = d_in[4];
    const void* cond_b   = d_in[5];
    const void* in_w     = d_in[6];
    const void* in_b     = d_in[7];
    const void* rs_w     = d_in[8];
    const void* rs_b     = d_in[9];
    const void* end_w    = d_in[10];
    const void* end_b    = d_in[11];

    char* W = (char*)d_ws;
    int* flag = (int*)(W + 0);
    u16* xA   = (u16*)(W + 256);                  // 16,777,216
    u16* oacc = (u16*)(W + 256 + 16777216);       // 16,777,216
    u16* acts = (u16*)(W + 256 + 33554432);       // 16,777,216
    u16* ctxt = (u16*)(W + 256 + 50331648);       //  6,291,456
    u16* Wc   = (u16*)(W + 256 + 56623104);       //  7,077,888
    u16* Wrs  = (u16*)(W + 256 + 63700992);       //  2,097,152
    u16* rsb  = (u16*)(W + 256 + 65798144);       //      8,192  -> total ~62.8 MiB

    probe_kernel<<<1, 256, 0, stream>>>((const u16*)forecast, flag);

    launch_prep<false>(forecast, context, start_w, start_b, cond_w, cond_b, in_w, in_b, rs_w,
                       rs_b, xA, ctxt, Wc, Wrs, rsb, flag, stream);
    launch_prep<true>(forecast, context, start_w, start_b, cond_w, cond_b, in_w, in_b, rs_w,
                      rs_b, xA, ctxt, Wc, Wrs, rsb, flag, stream);

    const int dil[NLAYERS] = {1, 2, 4, 8, 16, 32, 64, 128};
    for (int l = 0; l < NLAYERS; l++) {
        layer_conv<<<dim3(32, BATCH, 2), 512, 0, stream>>>(xA, Wc, ctxt, acts, l, dil[l]);
        layer_rs<<<dim3(32, BATCH, 2), 512, 0, stream>>>(acts, xA, Wrs, rsb, oacc, l,
                                                         l == 0, l == NLAYERS - 1);
    }

    end_kernel<false><<<128, 256, 0, stream>>>(oacc, end_w, end_b, forecast, d_out, flag);
    end_kernel<true><<<128, 256, 0, stream>>>(oacc, end_w, end_b, forecast, d_out, flag);
}

// Round 14
// 845.853 us; speedup vs baseline: 1.2779x; 1.2779x over previous
//
#include <hip/hip_runtime.h>

#define BATCH 8
#define T 4096
#define NCH 256
#define NCTX 80
#define NLAYERS 8

typedef unsigned short u16;
typedef __attribute__((ext_vector_type(8))) short short8;
typedef __attribute__((ext_vector_type(4))) short short4v;
typedef __attribute__((ext_vector_type(4))) float float4v;

__device__ __forceinline__ float b2f(u16 u) {
    unsigned v = ((unsigned)u) << 16;
    float f;
    __builtin_memcpy(&f, &v, 4);
    return f;
}
__device__ __forceinline__ u16 f2b(float f) {
    unsigned v;
    __builtin_memcpy(&v, &f, 4);
    unsigned r = v + 0x7FFFu + ((v >> 16) & 1u);
    return (u16)(r >> 16);
}

typedef const __attribute__((address_space(1))) unsigned int* gp1;
typedef __attribute__((address_space(3))) unsigned int* lp3;
__device__ __forceinline__ void gl_lds16(const u16* g, u16* l) {
    __builtin_amdgcn_global_load_lds((gp1)g, (lp3)l, 16, 0, 0);
}

// Inputs are fp32 (established: round 2's pure-bf16 interpretation NaN'd; the
// probe-gated rounds 3-13 always took the fp32 path). Hardcoded now.

// ---------------- convert fp32 -> bf16 ----------------
__global__ void cvt_kernel(const float* __restrict__ src, u16* __restrict__ dst, int n) {
    int i = blockIdx.x * 256 + threadIdx.x;
    if (i < n) dst[i] = f2b(src[i]);
}

// ---------------- build Wc [8][512][864] ----------------
__global__ void prep_wc(const float* __restrict__ in_w, const float* __restrict__ in_b,
                        const float* __restrict__ cond_w, const float* __restrict__ cond_b,
                        u16* __restrict__ Wc) {
    int row = blockIdx.x;  // 0..4095 = l*512+o
    for (int it = 0; it < 4; it++) {
        int col = it * 256 + threadIdx.x;
        if (col >= 864) break;
        float v;
        if (col < 256)       v = in_w[((size_t)row * 256 + col) * 3];
        else if (col < 512)  v = in_w[((size_t)row * 256 + (col - 256)) * 3 + 1];
        else if (col < 768)  v = in_w[((size_t)row * 256 + (col - 512)) * 3 + 2];
        else if (col < 848)  v = cond_w[(size_t)row * 80 + (col - 768)];
        else if (col == 848) v = in_b[row] + cond_b[row];
        else                 v = 0.f;
        Wc[(size_t)row * 864 + col] = f2b(v);
    }
}

// ---------------- transpose context -> ctx_t [B][T][96] ----------------
__global__ void prep_ctx(const float* __restrict__ ctx, u16* __restrict__ ctxt) {
    __shared__ float sm[80][65];
    const int tid = threadIdx.x;
    const int b = blockIdx.y, t0 = blockIdx.x * 64;
    for (int it = 0; it < 20; it++) {
        int e = it * 256 + tid;
        int j = e >> 6, tt = e & 63;
        sm[j][tt] = ctx[((size_t)b * 80 + j) * T + t0 + tt];
    }
    __syncthreads();
    for (int it = 0; it < 24; it++) {
        int e = it * 256 + tid;
        int r = e / 96, c = e - r * 96;
        float v = (c < 80) ? sm[c][r] : (c == 80 ? 1.f : 0.f);
        ctxt[((size_t)b * T + t0 + r) * 96 + c] = f2b(v);
    }
}

// ---------------- start conv (4 -> 256, 1x1) -> x_t [B][T][256] ----------------
__global__ void start_kernel(const float* __restrict__ fc, const float* __restrict__ w,
                             const float* __restrict__ bias, u16* __restrict__ xt) {
    __shared__ float fsm[4][64];
    __shared__ float wsm[1024];
    __shared__ float bsm[256];
    const int tid = threadIdx.x;
    const int b = blockIdx.y, t0 = blockIdx.x * 64;
    fsm[tid >> 6][tid & 63] = fc[((size_t)b * 8 + (tid >> 6)) * T + t0 + (tid & 63)];
    for (int it = 0; it < 4; it++) wsm[it * 256 + tid] = w[it * 256 + tid];
    bsm[tid] = bias[tid];
    __syncthreads();
    for (int r = 0; r < 64; r++) {
        int c = tid;
        float a = bsm[c];
#pragma unroll
        for (int k = 0; k < 4; k++) a += wsm[c * 4 + k] * fsm[k][r];
        xt[((size_t)b * T + t0 + r) * 256 + c] = f2b(a);
    }
}

// ================= layer conv kernel: dilated conv+cond GEMM + gate -> acts =================
// grid (T/128=32, B=8), 512 threads (8 waves). M=128t, N=512out, K=864.
// Chunks: 27 K-steps x 2 out-halves = 54. B dbuf 2x16KB, A triple-buf 3x8KB.
// Per-chunk: frag ds_reads -> issue DMA(c+1) -> MFMA -> barrier. Static acc indexing
// (runtime acc pointer = accvgpr shuttle regression, round 11).
// Bank swizzle perm(row)=(row>>1)&3: rows at +-4 no longer collide (the old
// (row&3) perm left a 4-way conflict = 17K cyc/CU measured in round 12).
__global__ __launch_bounds__(512, 1) void layer_conv(
    const u16* __restrict__ x, const u16* __restrict__ Wc, const u16* __restrict__ ctxt,
    u16* __restrict__ acts, int layer, int dil) {
    __shared__ u16 lds[28672];
    const int tid = threadIdx.x;
    const int w = tid >> 6, lane = tid & 63;
    const int l15 = lane & 15, quad = lane >> 4;
    const int iw = w >> 1, jc = w & 1;   // wave tile: t-rows 32*iw, out-cols 128*jc (per half)
    const int b = blockIdx.y, t0 = blockIdx.x * 128;
    const int lrow = lane >> 2;                          // 0..15
    const int lsw = (((lane & 3) ^ ((lane >> 3) & 3)) * 8);  // writer chunk swizzle
    const int rq = ((quad ^ ((l15 >> 1) & 3)) * 8);          // reader chunk swizzle

    const u16* xb = x + (size_t)b * T * 256;
    const u16* cb = ctxt + (size_t)b * T * 96;
    const u16* Wl = Wc + (size_t)layer * 512 * 864;

    float4v acc0[2][8], acc1[2][8];  // [m][jj]: acc0 = tanh half, acc1 = sigm half
#pragma unroll
    for (int m = 0; m < 2; m++)
#pragma unroll
        for (int jj = 0; jj < 8; jj++) {
            acc0[m][jj] = (float4v){0.f, 0.f, 0.f, 0.f};
            acc1[m][jj] = (float4v){0.f, 0.f, 0.f, 0.f};
        }

    auto stageA = [&](int s, int abuf) {  // 128 rows x 32 u16; wave w stages rows 16w..16w+16
        u16* dst = &lds[abuf * 4096 + w * 512];
        if (s < 24) {
            int seg = s >> 3, cs = s & 7;
            int tb = t0 + 16 * w + (seg - 1) * dil;
            if (tb >= 0 && tb + 16 <= T) {
                gl_lds16(xb + (size_t)(tb + lrow) * 256 + cs * 32 + lsw, dst);
            } else {  // boundary tile: manual masked path (rare)
                int t = tb + lrow;
                short8 av = (short8){0, 0, 0, 0, 0, 0, 0, 0};
                if (t >= 0 && t < T)
                    av = *(const short8*)(xb + (size_t)t * 256 + cs * 32 + lsw);
                *(short4v*)&dst[lane * 8] = __builtin_shufflevector(av, av, 0, 1, 2, 3);
                *(short4v*)&dst[lane * 8 + 4] = __builtin_shufflevector(av, av, 4, 5, 6, 7);
            }
        } else {
            gl_lds16(cb + (size_t)(t0 + 16 * w + lrow) * 96 + (s - 24) * 32 + lsw, dst);
        }
    };
    auto stageB = [&](int c) {  // 256 rows (out-half) x 32 u16; wave w: rows 32w..32w+32
        int s = c >> 1;
        const u16* src = Wl + (size_t)((c & 1) * 256 + 32 * w + lrow) * 864 + s * 32 + lsw;
        u16* dst = &lds[12288 + (c & 1) * 8192 + w * 1024];
        gl_lds16(src, dst);
        gl_lds16(src + (size_t)16 * 864, dst + 512);
    };

    stageA(0, 0);
    stageA(1, 1);
    stageB(0);
    __syncthreads();
    short8 af0, af1;  // A-fragments reused across the even/odd half-pair (same K-step)
#pragma unroll 1
    for (int c = 0; c < 54; c++) {
        int s = c >> 1;
        const u16* bB = &lds[12288 + (c & 1) * 8192];
        if ((c & 1) == 0) {  // read A only once per K-step
            const u16* bA = &lds[(s % 3) * 4096];
            af0 = *(const short8*)&bA[(32 * iw + l15) * 32 + rq];
            af1 = *(const short8*)&bA[(32 * iw + 16 + l15) * 32 + rq];
        }
        short8 bf[8];
#pragma unroll
        for (int jj = 0; jj < 8; jj++)
            bf[jj] = *(const short8*)&bB[(128 * jc + 16 * jj + l15) * 32 + rq];
        if ((c & 1) == 0 && s + 2 < 27) stageA(s + 2, (s + 2) % 3);
        if (c + 1 < 54) stageB(c + 1);
        if ((c & 1) == 0) {
#pragma unroll
            for (int jj = 0; jj < 8; jj++) {
                acc0[0][jj] = __builtin_amdgcn_mfma_f32_16x16x32_bf16(af0, bf[jj], acc0[0][jj], 0, 0, 0);
                acc0[1][jj] = __builtin_amdgcn_mfma_f32_16x16x32_bf16(af1, bf[jj], acc0[1][jj], 0, 0, 0);
            }
        } else {
#pragma unroll
            for (int jj = 0; jj < 8; jj++) {
                acc1[0][jj] = __builtin_amdgcn_mfma_f32_16x16x32_bf16(af0, bf[jj], acc1[0][jj], 0, 0, 0);
                acc1[1][jj] = __builtin_amdgcn_mfma_f32_16x16x32_bf16(af1, bf[jj], acc1[1][jj], 0, 0, 0);
            }
        }
        __syncthreads();
    }

    // gate + store acts[b][t][o]
    u16* ab = acts + (size_t)b * T * 256;
#pragma unroll
    for (int m = 0; m < 2; m++)
#pragma unroll
        for (int jj = 0; jj < 8; jj++) {
            int o = 128 * jc + 16 * jj + l15;
#pragma unroll
            for (int r = 0; r < 4; r++) {
                int t = t0 + 32 * iw + 16 * m + quad * 4 + r;
                float at = acc0[m][jj][r], as = acc1[m][jj][r];
                float e2 = __expf(2.f * at);
                float th = 1.f - 2.f / (e2 + 1.f);
                float sg = 1.f / (1.f + __expf(-as));
                ab[(size_t)t * 256 + o] = f2b(th * sg);
            }
        }
}

// ================= layer rs kernel: 1x1 conv (K=256) + residual/skip update =================
// Same skeleton; 8 K-steps x 2 halves = 16 chunks. x updated in place (own tile).
__global__ __launch_bounds__(512, 1) void layer_rs(
    const u16* __restrict__ acts, u16* __restrict__ x, const u16* __restrict__ Wrs,
    const u16* __restrict__ rsb, u16* __restrict__ oacc, int layer, int first, int last) {
    __shared__ u16 lds[28672];
    const int tid = threadIdx.x;
    const int w = tid >> 6, lane = tid & 63;
    const int l15 = lane & 15, quad = lane >> 4;
    const int iw = w >> 1, jc = w & 1;
    const int b = blockIdx.y, t0 = blockIdx.x * 128;
    const int lrow = lane >> 2;
    const int lsw = (((lane & 3) ^ ((lane >> 3) & 3)) * 8);
    const int rq = ((quad ^ ((l15 >> 1) & 3)) * 8);

    const u16* ab = acts + (size_t)b * T * 256;
    const u16* Wr = Wrs + (size_t)layer * 512 * 256;

    float4v acc0[2][8], acc1[2][8];
#pragma unroll
    for (int m = 0; m < 2; m++)
#pragma unroll
        for (int jj = 0; jj < 8; jj++) {
            acc0[m][jj] = (float4v){0.f, 0.f, 0.f, 0.f};
            acc1[m][jj] = (float4v){0.f, 0.f, 0.f, 0.f};
        }

    auto stageA = [&](int s, int abuf) {
        gl_lds16(ab + (size_t)(t0 + 16 * w + lrow) * 256 + s * 32 + lsw,
                 &lds[abuf * 4096 + w * 512]);
    };
    auto stageB = [&](int c) {
        int s = c >> 1;
        const u16* src = Wr + (size_t)((c & 1) * 256 + 32 * w + lrow) * 256 + s * 32 + lsw;
        u16* dst = &lds[12288 + (c & 1) * 8192 + w * 1024];
        gl_lds16(src, dst);
        gl_lds16(src + (size_t)16 * 256, dst + 512);
    };

    stageA(0, 0);
    stageA(1, 1);
    stageB(0);
    __syncthreads();
    short8 af0, af1;
#pragma unroll 1
    for (int c = 0; c < 16; c++) {
        int s = c >> 1;
        const u16* bB = &lds[12288 + (c & 1) * 8192];
        if ((c & 1) == 0) {
            const u16* bA = &lds[(s % 3) * 4096];
            af0 = *(const short8*)&bA[(32 * iw + l15) * 32 + rq];
            af1 = *(const short8*)&bA[(32 * iw + 16 + l15) * 32 + rq];
        }
        short8 bf[8];
#pragma unroll
        for (int jj = 0; jj < 8; jj++)
            bf[jj] = *(const short8*)&bB[(128 * jc + 16 * jj + l15) * 32 + rq];
        if ((c & 1) == 0 && s + 2 < 8) stageA(s + 2, (s + 2) % 3);
        if (c + 1 < 16) stageB(c + 1);
        if ((c & 1) == 0) {
#pragma unroll
            for (int jj = 0; jj < 8; jj++) {
                acc0[0][jj] = __builtin_amdgcn_mfma_f32_16x16x32_bf16(af0, bf[jj], acc0[0][jj], 0, 0, 0);
                acc0[1][jj] = __builtin_amdgcn_mfma_f32_16x16x32_bf16(af1, bf[jj], acc0[1][jj], 0, 0, 0);
            }
        } else {
#pragma unroll
            for (int jj = 0; jj < 8; jj++) {
                acc1[0][jj] = __builtin_amdgcn_mfma_f32_16x16x32_bf16(af0, bf[jj], acc1[0][jj], 0, 0, 0);
                acc1[1][jj] = __builtin_amdgcn_mfma_f32_16x16x32_bf16(af1, bf[jj], acc1[1][jj], 0, 0, 0);
            }
        }
        __syncthreads();
    }

    u16* xv = x + (size_t)b * T * 256;
    u16* oo = oacc + (size_t)b * T * 256;
#pragma unroll
    for (int m = 0; m < 2; m++)
#pragma unroll
        for (int jj = 0; jj < 8; jj++) {
            int o = 128 * jc + 16 * jj + l15;
            float b0 = b2f(rsb[layer * 512 + o]);
            float b1 = b2f(rsb[layer * 512 + 256 + o]);
#pragma unroll
            for (int r = 0; r < 4; r++) {
                int t = t0 + 32 * iw + 16 * m + quad * 4 + r;
                size_t idx = (size_t)t * 256 + o;
                float v0 = acc0[m][jj][r] + b0;
                if (last) {
                    oo[idx] = f2b(b2f(oo[idx]) + v0);  // last: rs[:256] -> skip
                } else {
                    xv[idx] = f2b(b2f(xv[idx]) + v0);  // residual (in place, own tile)
                    float v1 = acc1[m][jj][r] + b1;
                    oo[idx] = first ? f2b(v1) : f2b(b2f(oo[idx]) + v1);
                }
            }
        }
}

// ---------------- end conv (256 -> 8) + affine + output assembly (fp32 out) ----------------
__global__ void end_kernel(const u16* __restrict__ oacc, const float* __restrict__ w_end,
                           const float* __restrict__ b_end, const float* __restrict__ fc,
                           float* __restrict__ out) {
    __shared__ float wsm[2048];
    __shared__ float bsm[8];
    const int tid = threadIdx.x;
    for (int it = 0; it < 8; it++) wsm[it * 256 + tid] = w_end[it * 256 + tid];
    if (tid < 8) bsm[tid] = b_end[tid];
    __syncthreads();
    int gid = blockIdx.x * 256 + tid;  // 0..32767
    int b = gid >> 12, t = gid & 4095;
    float o8[8];
#pragma unroll
    for (int o = 0; o < 8; o++) o8[o] = bsm[o];
    const u16* orow = oacc + (size_t)(b * T + t) * 256;
    for (int c8 = 0; c8 < 32; c8++) {
        short8 v8 = *(const short8*)(orow + c8 * 8);
#pragma unroll
        for (int k = 0; k < 8; k++) {
            float v = b2f((u16)v8[k]);
            int c = c8 * 8 + k;
#pragma unroll
            for (int o = 0; o < 8; o++) o8[o] += wsm[o * 256 + c] * v;
        }
    }
    size_t ob8 = (size_t)b * 8 * T;
#pragma unroll
    for (int j = 0; j < 4; j++) {
        float f1v = fc[ob8 + (size_t)(4 + j) * T + t];
        float ls = o8[4 + j];
        float val = __expf(ls) * f1v + o8[j];
        out[ob8 + (size_t)j * T + t] = fc[ob8 + (size_t)j * T + t];  // f0 bit-exact
        out[ob8 + (size_t)(4 + j) * T + t] = val;
        out[(size_t)BATCH * 8 * T + ((size_t)b * 4 + j) * T + t] = ls;
    }
}

extern "C" void kernel_launch(void* const* d_in, const int* in_sizes, int n_in,
                              void* d_out, int out_size, void* d_ws, size_t ws_size,
                              hipStream_t stream) {
    const float* forecast = (const float*)d_in[0];
    const float* context  = (const float*)d_in[1];
    const float* start_w  = (const float*)d_in[2];
    const float* start_b  = (const float*)d_in[3];
    const float* cond_w   = (const float*)d_in[4];
    const float* cond_b   = (const float*)d_in[5];
    const float* in_w     = (const float*)d_in[6];
    const float* in_b     = (const float*)d_in[7];
    const float* rs_w     = (const float*)d_in[8];
    const float* rs_b     = (const float*)d_in[9];
    const float* end_w    = (const float*)d_in[10];
    const float* end_b    = (const float*)d_in[11];

    char* W = (char*)d_ws;
    u16* xA   = (u16*)(W + 0);                    // 16,777,216
    u16* oacc = (u16*)(W + 16777216);             // 16,777,216
    u16* acts = (u16*)(W + 33554432);             // 16,777,216
    u16* ctxt = (u16*)(W + 50331648);             //  6,291,456
    u16* Wc   = (u16*)(W + 56623104);             //  7,077,888
    u16* Wrs  = (u16*)(W + 63700992);             //  2,097,152
    u16* rsb  = (u16*)(W + 65798144);             //      8,192  -> total ~62.8 MiB

    cvt_kernel<<<4096, 256, 0, stream>>>(rs_w, Wrs, 8 * 512 * 256);
    cvt_kernel<<<16, 256, 0, stream>>>(rs_b, rsb, 4096);
    prep_wc<<<4096, 256, 0, stream>>>(in_w, in_b, cond_w, cond_b, Wc);
    prep_ctx<<<dim3(64, BATCH), 256, 0, stream>>>(context, ctxt);
    start_kernel<<<dim3(64, BATCH), 256, 0, stream>>>(forecast, start_w, start_b, xA);

    const int dil[NLAYERS] = {1, 2, 4, 8, 16, 32, 64, 128};
    for (int l = 0; l < NLAYERS; l++) {
        layer_conv<<<dim3(32, BATCH), 512, 0, stream>>>(xA, Wc, ctxt, acts, l, dil[l]);
        layer_rs<<<dim3(32, BATCH), 512, 0, stream>>>(acts, xA, Wrs, rsb, oacc, l,
                                                      l == 0, l == NLAYERS - 1);
    }

    end_kernel<<<128, 256, 0, stream>>>(oacc, end_w, end_b, forecast, (float*)d_out);
}